// Round 10
// baseline (214.916 us; speedup 1.0000x reference)
//
#include <hip/hip_runtime.h>
#include <math.h>

#define T_SEQ 34
#define NTOK 14
#define NE (T_SEQ * NTOK) // 476
#define ROWS 30           // rows per block (two 15-row groups)
#define HR 15             // half-rows: threads own (t, r) and (t, r+15)
#define BLK 512
#define NEL (ROWS * T_SEQ) // 1020 elements per block
#define TTS 31            // toksT row stride: banks (31s+r)%32, conflict-free

// Single-phase, t-major, 2 elements/thread (same t => identical loop bounds,
// 2x ILP in the attention loop). Tables built once per 1020 elements.
__global__ __launch_bounds__(BLK) void micro_fused_kernel(
    const int* __restrict__ idx,
    const float* __restrict__ tok_emb,
    const float* __restrict__ s_amp, const float* __restrict__ s_phase,
    const float* __restrict__ s_slope, const float* __restrict__ s_offset,
    const float* __restrict__ pc_slope, const float* __restrict__ pc_int,
    const float* __restrict__ z_hi, const float* __restrict__ spec,
    const float* __restrict__ q_w, const float* __restrict__ v_w,
    const float* __restrict__ out_A, const float* __restrict__ out_B,
    const float* __restrict__ q_phase,
    const float* __restrict__ ln1_w, const float* __restrict__ ln2_w,
    const float* __restrict__ lnf_w,
    const float* __restrict__ fc1_w, const float* __restrict__ fc1_b,
    const float* __restrict__ fc2_w, const float* __restrict__ fc2_b,
    const float* __restrict__ head_w,
    float* __restrict__ out, int N)
{
    __shared__ float4 H4[NE];      // (h2,h3,h4,h0) RMS-normed
    __shared__ float  H1f[NE];     // h1
    __shared__ float4 C3[NE];      // q_w^T @ q_rot * invsqrt(5) * log2(e)
    __shared__ int    toksT[T_SEQ * TTS];
    alignas(16) __shared__ float PosT[T_SEQ * 3];
    alignas(16) __shared__ float TE[NTOK * 2];
    alignas(16) __shared__ float PMs[12];
    alignas(16) __shared__ float Ws2[NTOK * 8];  // lnf-folded: Ws2[v][d] = lnf[d]*(head_w.T@tok_emb.T)[d][v]
    alignas(16) __shared__ float ln2s[8], fc1ws[12], fc2ws[12], fc2bs[8];
    __shared__ float fc1bs[2];

    const int tid = threadIdx.x;
    const int elemBase = blockIdx.x * NEL;

    // ---- stage tokens (coalesced read, transposed store, stride 31) ----
    for (int i = tid; i < NEL; i += BLK) {
        int g = elemBase + i;
        int v = (g < N) ? idx[g] : 0;
        int r = i / T_SEQ, s = i - r * T_SEQ;
        toksT[s * TTS + r] = v;
    }

    // ---- build per-(t,tok) tables (R3/R9-proven math) ----
    if (tid < NE) {
        const float amp = s_amp[0], ph = s_phase[0], slp = s_slope[0], off = s_offset[0];
        const float pcs = pc_slope[0], pci = pc_int[0];
        const float cph = cosf(q_phase[0]), sph = sinf(q_phase[0]);
        const float cscale = 0.44721359549995793f * 1.4426950408889634f; // 1/sqrt(5)*log2e
        const int e = tid;
        const int t = e / NTOK, tk = e - t * NTOK;
        float px, py, pz;
        if (t == 33)      { px = 0.f;     py = 0.f;     pz = 0.f; }
        else if (t == 32) { px = z_hi[0]; py = z_hi[1]; pz = z_hi[2]; }
        else if (t == 10) { px = spec[0]; py = spec[1]; pz = spec[2]; }
        else if (t == 21) { px = spec[3]; py = spec[4]; pz = spec[5]; }
        else {
            int i = (t < 10) ? t : (t < 21 ? t - 11 : t - 22);
            float fi = (float)i;
            float ang = 0.62831853071795864769f * fi + ph;
            float mlt = 1.f + pci + pcs * fi;
            px = amp * cosf(ang) * mlt;
            py = amp * sinf(ang) * mlt;
            pz = (slp * fi + off) * mlt;
        }
        if (tk == 0) { PosT[t*3] = px; PosT[t*3+1] = py; PosT[t*3+2] = pz; }
        float x0 = tok_emb[tk * 2], x1 = tok_emb[tk * 2 + 1];
        float ssum = x0*x0 + x1*x1 + px*px + py*py + pz*pz;
        float rn = rsqrtf(ssum * 0.2f + 1e-5f);
        float h0 = x0 * rn * ln1_w[0], h1 = x1 * rn * ln1_w[1];
        float h2 = px * rn * ln1_w[2], h3 = py * rn * ln1_w[3], h4 = pz * rn * ln1_w[4];
        float q0 = q_w[0]  * h2 + q_w[1]  * h3 + q_w[2]  * h4;
        float q1 = q_w[3]  * h2 + q_w[4]  * h3 + q_w[5]  * h4;
        float q2 = q_w[6]  * h2 + q_w[7]  * h3 + q_w[8]  * h4;
        float q3 = q_w[9]  * h2 + q_w[10] * h3 + q_w[11] * h4;
        float q4 = q_w[12] * h2 + q_w[13] * h3 + q_w[14] * h4;
        float r0 = q0 * cph - q1 * sph, r1 = q0 * sph + q1 * cph;
        float r2c = q2 * cph - q3 * sph, r3 = q2 * sph + q3 * cph;
        float c0 = (r0*q_w[0] + r1*q_w[3] + r2c*q_w[6] + r3*q_w[9]  + q4*q_w[12]) * cscale;
        float c1 = (r0*q_w[1] + r1*q_w[4] + r2c*q_w[7] + r3*q_w[10] + q4*q_w[13]) * cscale;
        float c2 = (r0*q_w[2] + r1*q_w[5] + r2c*q_w[8] + r3*q_w[11] + q4*q_w[14]) * cscale;
        H4[e] = make_float4(h2, h3, h4, h0);
        H1f[e] = h1;
        C3[e] = make_float4(c0, c1, c2, 0.f);
    }
    if (tid < 28) TE[tid] = tok_emb[tid];
    if (tid < 70) { // Ws2[v][d] = lnf[d] * sum_c head_w[c*5+d]*tok_emb[v*2+c]
        int v = tid / 5, d = tid - v * 5;
        Ws2[v * 8 + d] = lnf_w[d] * (head_w[d] * tok_emb[v * 2]
                                   + head_w[5 + d] * tok_emb[v * 2 + 1]);
    }
    if (tid < 10) { // PM[j][c] = sum_i (out_A@out_B)[i][j] * v_w[i*2+c]
        int j = tid >> 1, c = tid & 1;
        float acc = 0.f;
        for (int i = 0; i < 5; ++i) {
            float m5 = out_A[i*2] * out_B[j] + out_A[i*2+1] * out_B[5 + j];
            acc += m5 * v_w[i*2 + c];
        }
        PMs[tid] = acc;
    }
    if (tid < 5)  { ln2s[tid] = ln2_w[tid]; fc2bs[tid] = fc2_b[tid]; }
    if (tid < 10) { fc1ws[tid] = fc1_w[tid]; fc2ws[tid] = fc2_w[tid]; }
    if (tid < 2)  { fc1bs[tid] = fc1_b[tid]; }

    __syncthreads();

    // ---- t-major, 2 elements/thread with the SAME t (identical loop bounds) ----
    if (tid >= HR * T_SEQ) return;     // 510 active threads
    const int t  = tid / HR;           // 0..33
    const int rA = tid - t * HR;       // 0..14
    const int rB = rA + HR;            // 15..29

    const int tokA = toksT[t * TTS + rA];
    const int tokB = toksT[t * TTS + rB];
    const float4 cA = C3[t * NTOK + tokA];
    const float4 cB = C3[t * NTOK + tokB];

    float lA = 0.f, aA0 = 0.f, aA1 = 0.f;
    float lB = 0.f, aB0 = 0.f, aB1 = 0.f;
#pragma unroll 4
    for (int s = 0; s <= t; ++s) {
        int ta = toksT[s * TTS + rA];
        int tb = toksT[s * TTS + rB];
        int eA = s * NTOK + ta;
        int eB = s * NTOK + tb;
        float4 hA = H4[eA]; float hA1 = H1f[eA];
        float4 hB = H4[eB]; float hB1 = H1f[eB];
        float scA = fmaf(cA.x, hA.x, fmaf(cA.y, hA.y, cA.z * hA.z));
        float scB = fmaf(cB.x, hB.x, fmaf(cB.y, hB.y, cB.z * hB.z));
        float pA = __builtin_amdgcn_exp2f(scA);
        float pB = __builtin_amdgcn_exp2f(scB);
        lA += pA; aA0 = fmaf(pA, hA.w, aA0); aA1 = fmaf(pA, hA1, aA1);
        lB += pB; aB0 = fmaf(pB, hB.w, aB0); aB1 = fmaf(pB, hB1, aB1);
    }
    const float ilA = __builtin_amdgcn_rcpf(lA);
    const float ilB = __builtin_amdgcn_rcpf(lB);
    aA0 *= ilA; aA1 *= ilA;
    aB0 *= ilB; aB1 *= ilB;

    // ---- epilogue (runs twice, independent; lnf folded into Ws2) ----
    const float pxv = PosT[t*3], pyv = PosT[t*3+1], pzv = PosT[t*3+2];

    auto epi = [&](int r, int tok, float a0, float a1) {
        const int lin = elemBase + r * T_SEQ + t;
        if (lin >= N) return;
        float y[5];
        y[0] = TE[tok*2]   + PMs[0] * a0 + PMs[1] * a1;
        y[1] = TE[tok*2+1] + PMs[2] * a0 + PMs[3] * a1;
        y[2] = pxv + PMs[4] * a0 + PMs[5] * a1;
        y[3] = pyv + PMs[6] * a0 + PMs[7] * a1;
        y[4] = pzv + PMs[8] * a0 + PMs[9] * a1;

        float s2 = y[0]*y[0] + y[1]*y[1] + y[2]*y[2] + y[3]*y[3] + y[4]*y[4];
        float r2 = rsqrtf(s2 * 0.2f + 1e-5f);
        float hh[5];
#pragma unroll
        for (int j = 0; j < 5; ++j) hh[j] = y[j] * r2 * ln2s[j];

        float u0 = fc1bs[0], u1 = fc1bs[1];
#pragma unroll
        for (int j = 0; j < 5; ++j) { u0 += hh[j] * fc1ws[j]; u1 += hh[j] * fc1ws[5 + j]; }
        float g0 = 0.5f * u0 * (1.f + erff(u0 * 0.70710678118654752f));
        float g1v = 0.5f * u1 * (1.f + erff(u1 * 0.70710678118654752f));

        float y2[5]; float s3 = 0.f;
#pragma unroll
        for (int j = 0; j < 5; ++j) {
            y2[j] = y[j] + g0 * fc2ws[j * 2] + g1v * fc2ws[j * 2 + 1] + fc2bs[j];
            s3 += y2[j] * y2[j];
        }
        float r3 = rsqrtf(s3 * 0.2f + 1e-5f);

        float2* op = (float2*)(out + (size_t)lin * 14);
#pragma unroll
        for (int v = 0; v < 7; ++v) {
            float4 w0 = *(const float4*)&Ws2[(2*v) * 8];
            float  w4 = Ws2[(2*v) * 8 + 4];
            float4 u0v = *(const float4*)&Ws2[(2*v+1) * 8];
            float  u4 = Ws2[(2*v+1) * 8 + 4];
            float rAo = r3 * (y2[0]*w0.x + y2[1]*w0.y + y2[2]*w0.z + y2[3]*w0.w + y2[4]*w4);
            float rBo = r3 * (y2[0]*u0v.x + y2[1]*u0v.y + y2[2]*u0v.z + y2[3]*u0v.w + y2[4]*u4);
            op[v] = make_float2(rAo, rBo);
        }
    };

    epi(rA, tokA, aA0, aA1);
    epi(rB, tokB, aB0, aB1);
}

extern "C" void kernel_launch(void* const* d_in, const int* in_sizes, int n_in,
                              void* d_out, int out_size, void* d_ws, size_t ws_size,
                              hipStream_t stream) {
    const int N = in_sizes[0]; // B*T
    const int grid = (N + NEL - 1) / NEL;
    micro_fused_kernel<<<grid, BLK, 0, stream>>>(
        (const int*)d_in[0],
        (const float*)d_in[1], (const float*)d_in[2], (const float*)d_in[3],
        (const float*)d_in[4], (const float*)d_in[5], (const float*)d_in[6],
        (const float*)d_in[7], (const float*)d_in[8], (const float*)d_in[9],
        (const float*)d_in[10], (const float*)d_in[11], (const float*)d_in[12],
        (const float*)d_in[13], (const float*)d_in[14], (const float*)d_in[15],
        (const float*)d_in[16], (const float*)d_in[17], (const float*)d_in[18],
        (const float*)d_in[19], (const float*)d_in[20], (const float*)d_in[21],
        (const float*)d_in[22],
        (float*)d_out, N);
}